// Round 1
// baseline (381.731 us; speedup 1.0000x reference)
//
#include <hip/hip_runtime.h>

// SpatialTransformer: dense 2D bilinear warp with edge clamping.
// img: [B,C,H,W] fp32, trf: [B,2,H,W] fp32 (ij displacements), out: [B,C,H,W] fp32.
// B=16, C=4, H=W=768.

#define BB 16
#define CC 4
#define HH 768
#define WW 768
#define HWSZ (HH * WW)

__global__ __launch_bounds__(256) void st_warp_kernel(
    const float* __restrict__ img,
    const float* __restrict__ trf,
    float* __restrict__ out)
{
    int idx = blockIdx.x * blockDim.x + threadIdx.x;   // pixel index over B*H*W
    if (idx >= BB * HWSZ) return;

    int b = idx / HWSZ;
    int p = idx - b * HWSZ;
    int h = p / WW;
    int w = p - h * WW;

    // displacements: trf[b,0,h,w] = dy, trf[b,1,h,w] = dx
    const float* tb = trf + (size_t)b * 2 * HWSZ;
    float dy = tb[p];
    float dx = tb[p + HWSZ];

    float y = (float)h + dy;
    float x = (float)w + dx;

    const float maxy = (float)(HH - 1);
    const float maxx = (float)(WW - 1);

    // clipped sample location
    float cy = fminf(fmaxf(y, 0.0f), maxy);
    float cx = fminf(fmaxf(x, 0.0f), maxx);

    // floor / ceil corners (clamped)
    float f0y = fminf(fmaxf(floorf(y), 0.0f), maxy);
    float f0x = fminf(fmaxf(floorf(x), 0.0f), maxx);
    float f1y = fminf(f0y + 1.0f, maxy);
    float f1x = fminf(f0x + 1.0f, maxx);

    // neurite convention: d1 = loc1 - clipped = weight of FLOOR corner
    float wy0 = f1y - cy;        // weight for i0y
    float wx0 = f1x - cx;        // weight for i0x
    float wy1 = 1.0f - wy0;      // weight for i1y
    float wx1 = 1.0f - wx0;      // weight for i1x

    int i0y = (int)f0y;
    int i0x = (int)f0x;
    int i1y = (int)f1y;
    int i1x = (int)f1x;

    int o00 = i0y * WW + i0x;
    int o01 = i0y * WW + i1x;
    int o10 = i1y * WW + i0x;
    int o11 = i1y * WW + i1x;

    float w00 = wy0 * wx0;
    float w01 = wy0 * wx1;
    float w10 = wy1 * wx0;
    float w11 = wy1 * wx1;

    const float* ib = img + (size_t)b * CC * HWSZ;
    float* ob = out + (size_t)b * CC * HWSZ + p;

#pragma unroll
    for (int c = 0; c < CC; ++c) {
        const float* ic = ib + c * HWSZ;
        float v = w00 * ic[o00] + w01 * ic[o01] + w10 * ic[o10] + w11 * ic[o11];
        ob[c * HWSZ] = v;
    }
}

extern "C" void kernel_launch(void* const* d_in, const int* in_sizes, int n_in,
                              void* d_out, int out_size, void* d_ws, size_t ws_size,
                              hipStream_t stream) {
    const float* img = (const float*)d_in[0];
    const float* trf = (const float*)d_in[1];
    float* out = (float*)d_out;

    int npix = BB * HWSZ;                 // 9,437,184
    int block = 256;
    int grid = (npix + block - 1) / block; // 36,864
    st_warp_kernel<<<grid, block, 0, stream>>>(img, trf, out);
}

// Round 2
// 365.423 us; speedup vs baseline: 1.0446x; 1.0446x over previous
//
#include <hip/hip_runtime.h>

// SpatialTransformer: dense 2D bilinear warp with edge clamping.
// img: [B,C,H,W] fp32, trf: [B,2,H,W] fp32 (ij displacements), out: [B,C,H,W] fp32.
// B=16, C=4, H=W=768.
//
// R1: 2D tiling (64 wide x 16 tall per block, each thread owns 4 adjacent rows)
// for gather locality; XCD-swizzled block->tile map so vertical halo reuse hits
// one XCD's L2; nontemporal trf loads / out stores to keep L2 for img.

#define BB 16
#define CC 4
#define HH 768
#define WW 768
#define HWSZ (HH * WW)

#define TW 64
#define TH 16
#define RPT 4                      // rows per thread
#define NXT (WW / TW)              // 12 x-tiles
#define NYT (HH / TH)              // 48 y-tiles
#define TILES_PER_B (NXT * NYT)    // 576
#define NTILES (TILES_PER_B * BB)  // 9216
#define NXCD 8

__global__ __launch_bounds__(256) void st_warp_kernel(
    const float* __restrict__ img,
    const float* __restrict__ trf,
    float* __restrict__ out)
{
    // XCD-aware swizzle: block l lands on XCD l%8 (heuristic); give each XCD a
    // contiguous run of tiles. Tile order within the run walks ht fastest, so a
    // single XCD streams down a 64-wide column band -> vertical halo reuse in L2.
    int l = blockIdx.x;
    int xcd = l & (NXCD - 1);
    int t = xcd * (NTILES / NXCD) + (l >> 3);
    int b = t / TILES_PER_B;
    int rem = t - b * TILES_PER_B;
    int wt = rem / NYT;
    int ht = rem - wt * NYT;

    int tx = threadIdx.x & 63;          // 0..63 (one wave = one row: coalesced)
    int ty = threadIdx.x >> 6;          // 0..3
    int w = wt * TW + tx;
    int h_base = ht * TH + ty * RPT;    // each thread: rows h_base .. h_base+3

    const float maxy = (float)(HH - 1);
    const float maxx = (float)(WW - 1);

    const float* tb = trf + (size_t)b * 2 * HWSZ;
    const float* ib = img + (size_t)b * CC * HWSZ;
    float* ob = out + (size_t)b * CC * HWSZ;

#pragma unroll
    for (int r = 0; r < RPT; ++r) {
        int h = h_base + r;
        int p = h * WW + w;

        float dy = __builtin_nontemporal_load(tb + p);
        float dx = __builtin_nontemporal_load(tb + p + HWSZ);

        float y = (float)h + dy;
        float x = (float)w + dx;

        float cy = fminf(fmaxf(y, 0.0f), maxy);
        float cx = fminf(fmaxf(x, 0.0f), maxx);

        float f0y = fminf(fmaxf(floorf(y), 0.0f), maxy);
        float f0x = fminf(fmaxf(floorf(x), 0.0f), maxx);
        float f1y = fminf(f0y + 1.0f, maxy);
        float f1x = fminf(f0x + 1.0f, maxx);

        // neurite convention: weight of floor corner = loc1 - clipped
        float wy0 = f1y - cy;
        float wx0 = f1x - cx;
        float wy1 = 1.0f - wy0;
        float wx1 = 1.0f - wx0;

        int i0y = (int)f0y;
        int i0x = (int)f0x;
        int i1y = (int)f1y;
        int i1x = (int)f1x;

        int o00 = i0y * WW + i0x;
        int o01 = i0y * WW + i1x;
        int o10 = i1y * WW + i0x;
        int o11 = i1y * WW + i1x;

        float w00 = wy0 * wx0;
        float w01 = wy0 * wx1;
        float w10 = wy1 * wx0;
        float w11 = wy1 * wx1;

#pragma unroll
        for (int c = 0; c < CC; ++c) {
            const float* ic = ib + c * HWSZ;
            float v = w00 * ic[o00] + w01 * ic[o01]
                    + w10 * ic[o10] + w11 * ic[o11];
            __builtin_nontemporal_store(v, ob + c * HWSZ + p);
        }
    }
}

extern "C" void kernel_launch(void* const* d_in, const int* in_sizes, int n_in,
                              void* d_out, int out_size, void* d_ws, size_t ws_size,
                              hipStream_t stream) {
    const float* img = (const float*)d_in[0];
    const float* trf = (const float*)d_in[1];
    float* out = (float*)d_out;

    st_warp_kernel<<<NTILES, 256, 0, stream>>>(img, trf, out);
}